// Round 1
// baseline (116.196 us; speedup 1.0000x reference)
//
#include <hip/hip_runtime.h>
#include <hip/hip_bf16.h>

// Problem constants (from reference)
#define NN 8192
#define NC 81
#define FG 80
#define ND 100
#define SH 8              // compaction shards per class
#define CAPS 128          // per-(class,shard) capacity
#define CPADI 32          // ints per counter slot = 128 B (own cache line)
#define MAXK 384          // max candidates entering NMS; E[K]=235, sd~15
#define KW6 6             // MAXK/64 bitmask words
#define KROW 8            // padded row stride in u64 (64 B -> aligned b128)
#define BBOX_CLIP 4.135166556742356f   // ln(1000/16)

// ---------------------------------------------------------------------------
// Kernel 1: softmax + per-class box decode + clip + filter + compaction.
// (unchanged from R4 — need its counters to surface before touching it)
// ---------------------------------------------------------------------------
__global__ __launch_bounds__(256) void decode_kernel(
    const float* __restrict__ prop,     // [N,4]
    const float* __restrict__ logit,    // [N,81]
    const float* __restrict__ reg,      // [N,324]
    const int* __restrict__ ih, const int* __restrict__ iw,
    int* __restrict__ counts,           // [FG*SH*CPADI]
    float* __restrict__ boxes0,         // [FG,4]
    float* __restrict__ cbox,           // [FG,SH,CAPS,4]
    float* __restrict__ cscore)         // [FG,SH,CAPS]
{
    const int n = blockIdx.x * 4 + (threadIdx.x >> 6);
    const int shard = blockIdx.x & (SH - 1);
    const int lane = threadIdx.x & 63;
    const float* lrow = logit + (long)n * NC;

    float v1 = lrow[lane];
    float v2 = (lane < NC - 64) ? lrow[64 + lane] : -1e30f;
    float m = fmaxf(v1, v2);
#pragma unroll
    for (int off = 32; off; off >>= 1) m = fmaxf(m, __shfl_xor(m, off));
    float e = expf(v1 - m) + ((lane < NC - 64) ? expf(v2 - m) : 0.0f);
#pragma unroll
    for (int off = 32; off; off >>= 1) e += __shfl_xor(e, off);

    const float W = (float)iw[0];
    const float H = (float)ih[0];
    const float4 p = *(const float4*)(prop + n * 4);
    const float pw = p.z - p.x, ph = p.w - p.y;
    const float pcx = p.x + 0.5f * pw, pcy = p.y + 0.5f * ph;

    for (int c = 1 + lane; c <= FG; c += 64) {
        float score = expf(lrow[c] - m) / e;   // match jax.nn.softmax (divide)
        const float4 d = *(const float4*)(reg + (long)n * (NC * 4) + c * 4);
        float dx = d.x / 10.0f;
        float dy = d.y / 10.0f;
        float dw = fminf(d.z / 5.0f, BBOX_CLIP);
        float dh = fminf(d.w / 5.0f, BBOX_CLIP);
        float ncx = dx * pw + pcx;
        float ncy = dy * ph + pcy;
        float nw = expf(dw) * pw;
        float nh = expf(dh) * ph;
        float bx1 = ncx - 0.5f * nw, by1 = ncy - 0.5f * nh;
        float bx2 = ncx + 0.5f * nw, by2 = ncy + 0.5f * nh;
        bx1 = fminf(fmaxf(bx1, 0.0f), W);
        by1 = fminf(fmaxf(by1, 0.0f), H);
        bx2 = fminf(fmaxf(bx2, 0.0f), W);
        by2 = fminf(fmaxf(by2, 0.0f), H);
        bool keep = ((bx2 - bx1) >= 1.0f) && ((by2 - by1) >= 1.0f);

        if (n == 0) {
            float* b0 = boxes0 + (c - 1) * 4;
            b0[0] = bx1; b0[1] = by1; b0[2] = bx2; b0[3] = by2;
        }
        if (score >= 0.05f && keep) {
            const int slot = (c - 1) * SH + shard;
            int pos = atomicAdd(&counts[slot * CPADI], 1);
            if (pos < CAPS) {
                float* cb = cbox + ((long)slot * CAPS + pos) * 4;
                cb[0] = bx1; cb[1] = by1; cb[2] = bx2; cb[3] = by2;
                cscore[slot * CAPS + pos] = score;
            }
        }
    }
}

// ---------------------------------------------------------------------------
// Kernel 2: sorted + triangular suppression-bitmask NMS.
// One 1024-thread block (16 waves) per class.
// load -> float4-chunked rank sort -> register-column IoU matrix (triangular,
// one uniform b128 row broadcast per row) -> wave-0 straight-line scan.
// Output layout (float32): boxes[FG*ND*4] | scores[FG*ND] | labels | valid
// ---------------------------------------------------------------------------
__global__ __launch_bounds__(1024) void nms_kernel(
    const int* __restrict__ counts,
    const float* __restrict__ boxes0,
    const float* __restrict__ cbox,
    const float* __restrict__ cscore,
    float* __restrict__ out)
{
    __shared__ __align__(16) float  s_sc[MAXK];     // unsorted scores
    __shared__ float4 s_ubox[MAXK];                 // unsorted boxes
    __shared__ int    s_sidx[MAXK];                 // rank -> unsorted idx
    __shared__ float4 s_box[MAXK];                  // sorted boxes
    __shared__ float  s_ss[MAXK];                   // sorted scores
    __shared__ unsigned long long s_row[MAXK * KROW];  // suppression bits

    const int c = blockIdx.x;       // class label = c+1
    const int t = threadIdx.x;
    const int lane = t & 63;
    const int wv = t >> 6;

    int cnt0 = min(counts[(c * SH + 0) * CPADI], CAPS);
    int cnt1 = min(counts[(c * SH + 1) * CPADI], CAPS);
    int cnt2 = min(counts[(c * SH + 2) * CPADI], CAPS);
    int cnt3 = min(counts[(c * SH + 3) * CPADI], CAPS);
    int cnt4 = min(counts[(c * SH + 4) * CPADI], CAPS);
    int cnt5 = min(counts[(c * SH + 5) * CPADI], CAPS);
    int cnt6 = min(counts[(c * SH + 6) * CPADI], CAPS);
    int cnt7 = min(counts[(c * SH + 7) * CPADI], CAPS);
    int K = cnt0 + cnt1 + cnt2 + cnt3 + cnt4 + cnt5 + cnt6 + cnt7;
    if (K > MAXK) K = MAXK;
    const int KW = (K + 63) >> 6;

    // zero the suppression matrix (skipped triangular words must be 0)
    for (int i = t; i < MAXK * KROW; i += 1024) s_row[i] = 0ull;
    // zero tails: scores (rank-sort float4 chunks read past K) and sorted
    // boxes (register columns j>=K become zero boxes -> iou==0 -> no bit)
    for (int i = K + t; i < MAXK; i += 1024) {
        s_sc[i] = 0.0f;
        s_ss[i] = 0.0f;
        s_box[i] = make_float4(0.f, 0.f, 0.f, 0.f);
    }
    // load: thread t handles shard s = t>>7, entry i = t&127
    {
        const int s = t >> 7;
        const int i = t & (CAPS - 1);
        int mycnt = cnt0;
        if (s == 1) mycnt = cnt1; if (s == 2) mycnt = cnt2;
        if (s == 3) mycnt = cnt3; if (s == 4) mycnt = cnt4;
        if (s == 5) mycnt = cnt5; if (s == 6) mycnt = cnt6;
        if (s == 7) mycnt = cnt7;
        int offs = 0;
        if (s > 0) offs += cnt0; if (s > 1) offs += cnt1;
        if (s > 2) offs += cnt2; if (s > 3) offs += cnt3;
        if (s > 4) offs += cnt4; if (s > 5) offs += cnt5;
        if (s > 6) offs += cnt6;
        if (i < mycnt) {
            int d = offs + i;
            if (d < MAXK) {
                const long src = (long)(c * SH + s) * CAPS + i;
                s_sc[d] = cscore[src];
                s_ubox[d] = *(const float4*)(cbox + src * 4);
            }
        }
    }
    __syncthreads();

    // counting-rank sort, float4-chunked score reads
    if (t < K) {
        const float si = s_sc[t];
        const float4* s4 = (const float4*)s_sc;
        const int nch = (K + 3) >> 2;
        int r = 0;
        for (int ch = 0; ch < nch; ++ch) {
            const float4 sj = s4[ch];
            const int j = ch * 4;
            r += (sj.x > si) || (sj.x == si && (j + 0) < t);
            r += (sj.y > si) || (sj.y == si && (j + 1) < t);
            r += (sj.z > si) || (sj.z == si && (j + 2) < t);
            r += (sj.w > si) || (sj.w == si && (j + 3) < t);
        }
        s_sidx[r] = t;
    }
    __syncthreads();

    if (t < K) {
        const int i = s_sidx[t];
        s_box[t] = s_ubox[i];
        s_ss[t] = s_sc[i];
    }
    __syncthreads();

    // register-resident columns: lane owns cols lane, 64+lane, ..., 320+lane
    float4 colb[KW6];
    float a2c[KW6];
#pragma unroll
    for (int w = 0; w < KW6; ++w) {
        const float4 b = s_box[w * 64 + lane];
        colb[w] = b;
        a2c[w] = (b.z - b.x) * (b.w - b.y);
    }

    // triangular suppression matrix: row r, bit j set iff j>r and iou>0.5
    for (int r = wv; r < K; r += 16) {
        const float4 rb = s_box[r];           // uniform b128 broadcast
        const float a1 = (rb.z - rb.x) * (rb.w - rb.y);
        const int w0 = r >> 6;
#pragma unroll
        for (int w = 0; w < KW6; ++w) {
            if (w >= w0 && w < KW) {
                const int j = w * 64 + lane;
                const float lx = fmaxf(rb.x, colb[w].x);
                const float ly = fmaxf(rb.y, colb[w].y);
                const float rx = fminf(rb.z, colb[w].z);
                const float ry = fminf(rb.w, colb[w].w);
                const float cw = fmaxf(rx - lx, 0.0f);
                const float ch = fmaxf(ry - ly, 0.0f);
                const float inter = cw * ch;
                const float iou = inter / (a1 + a2c[w] - inter + 1e-12f);
                const bool sup = (iou > 0.5f) && (j > r);
                const unsigned long long msk = __ballot(sup);
                if (lane == 0) s_row[r * KROW + w] = msk;
            }
        }
    }
    __syncthreads();

    if (wv != 0) return;    // scan + output: wave 0 only

    float* ob = out + (long)c * ND * 4;
    float* os = out + (long)FG * ND * 4 + c * ND;
    float* ol = os + FG * ND;
    float* ov = ol + FG * ND;
    const float lab = (float)(c + 1);

    unsigned long long aw0, aw1, aw2, aw3, aw4, aw5;
#define INIW(W) ((K >= (W)*64 + 64) ? ~0ull : ((K <= (W)*64) ? 0ull : ((~0ull) >> (64 - (K - (W)*64)))))
    aw0 = INIW(0); aw1 = INIW(1); aw2 = INIW(2);
    aw3 = INIW(3); aw4 = INIW(4); aw5 = INIW(5);
#undef INIW

    int kept = 0;
#define SWEEP(W, AW)                                                        \
    while (AW != 0 && kept < ND) {                                          \
        const int b_ = __builtin_ctzll(AW);                                 \
        const int i_ = (W) * 64 + b_;                                       \
        const unsigned long long* rp_ = s_row + i_ * KROW;                  \
        unsigned long long q0_ = rp_[0], q1_ = rp_[1], q2_ = rp_[2],        \
                           q3_ = rp_[3], q4_ = rp_[4], q5_ = rp_[5];        \
        if (lane == 0) {                                                    \
            const float4 kb = s_box[i_];                                    \
            ob[kept * 4 + 0] = kb.x; ob[kept * 4 + 1] = kb.y;               \
            ob[kept * 4 + 2] = kb.z; ob[kept * 4 + 3] = kb.w;               \
            os[kept] = s_ss[i_]; ol[kept] = lab; ov[kept] = 1.0f;           \
        }                                                                   \
        kept++;                                                             \
        aw0 &= ~q0_; aw1 &= ~q1_; aw2 &= ~q2_;                              \
        aw3 &= ~q3_; aw4 &= ~q4_; aw5 &= ~q5_;                              \
        AW &= ~(1ull << b_);  /* consume kept bit (triangular: no self bit) */ \
    }
    SWEEP(0, aw0) SWEEP(1, aw1) SWEEP(2, aw2)
    SWEEP(3, aw3) SWEEP(4, aw4) SWEEP(5, aw5)
#undef SWEEP

    // filler for invalid slots: boxes[0], score 0, valid 0
    const float b0x1 = boxes0[c * 4 + 0], b0y1 = boxes0[c * 4 + 1];
    const float b0x2 = boxes0[c * 4 + 2], b0y2 = boxes0[c * 4 + 3];
    for (int d = kept + lane; d < ND; d += 64) {
        ob[d * 4 + 0] = b0x1; ob[d * 4 + 1] = b0y1;
        ob[d * 4 + 2] = b0x2; ob[d * 4 + 3] = b0y2;
        os[d] = 0.0f; ol[d] = lab; ov[d] = 0.0f;
    }
}

extern "C" void kernel_launch(void* const* d_in, const int* in_sizes, int n_in,
                              void* d_out, int out_size, void* d_ws, size_t ws_size,
                              hipStream_t stream) {
    const float* prop  = (const float*)d_in[0];
    const float* logit = (const float*)d_in[1];
    const float* reg   = (const float*)d_in[2];
    const int*   ih    = (const int*)d_in[3];
    const int*   iw    = (const int*)d_in[4];
    float* out = (float*)d_out;

    char* ws = (char*)d_ws;
    int*   counts = (int*)ws;                        // FG*SH*CPADI ints (80 KB)
    float* boxes0 = (float*)(ws + 81920);            // FG*4 floats
    float* cscore = (float*)(ws + 90112);            // FG*SH*CAPS floats (320 KB)
    float* cbox   = (float*)(ws + 90112 + (size_t)FG * SH * CAPS * 4); // x4 (1.3 MB)

    hipMemsetAsync(counts, 0, FG * SH * CPADI * sizeof(int), stream);
    decode_kernel<<<NN / 4, 256, 0, stream>>>(prop, logit, reg, ih, iw,
                                              counts, boxes0, cbox, cscore);
    nms_kernel<<<FG, 1024, 0, stream>>>(counts, boxes0, cbox, cscore, out);
}

// Round 2
// 106.677 us; speedup vs baseline: 1.0892x; 1.0892x over previous
//
#include <hip/hip_runtime.h>
#include <hip/hip_bf16.h>

// Problem constants (from reference)
#define NN 8192
#define NC 81
#define FG 80
#define ND 100
#define SH 8              // compaction shards per class
#define CAPS 128          // per-(class,shard) capacity
#define CPADI 32          // ints per counter slot = 128 B (own cache line)
#define MAXK 384          // max candidates entering NMS; E[K]=235, sd~15
#define KW6 6             // MAXK/64 bitmask words
#define KROW 9            // row stride in u64 (72 B) -> <=4-way bank aliasing on column reads
#define BBOX_CLIP 4.135166556742356f   // ln(1000/16)

// ---------------------------------------------------------------------------
// Kernel 1: softmax + per-class box decode + clip + filter + compaction.
// (unchanged — not the bottleneck per R1 counters)
// ---------------------------------------------------------------------------
__global__ __launch_bounds__(256) void decode_kernel(
    const float* __restrict__ prop,     // [N,4]
    const float* __restrict__ logit,    // [N,81]
    const float* __restrict__ reg,      // [N,324]
    const int* __restrict__ ih, const int* __restrict__ iw,
    int* __restrict__ counts,           // [FG*SH*CPADI]
    float* __restrict__ boxes0,         // [FG,4]
    float* __restrict__ cbox,           // [FG,SH,CAPS,4]
    float* __restrict__ cscore)         // [FG,SH,CAPS]
{
    const int n = blockIdx.x * 4 + (threadIdx.x >> 6);
    const int shard = blockIdx.x & (SH - 1);
    const int lane = threadIdx.x & 63;
    const float* lrow = logit + (long)n * NC;

    float v1 = lrow[lane];
    float v2 = (lane < NC - 64) ? lrow[64 + lane] : -1e30f;
    float m = fmaxf(v1, v2);
#pragma unroll
    for (int off = 32; off; off >>= 1) m = fmaxf(m, __shfl_xor(m, off));
    float e = expf(v1 - m) + ((lane < NC - 64) ? expf(v2 - m) : 0.0f);
#pragma unroll
    for (int off = 32; off; off >>= 1) e += __shfl_xor(e, off);

    const float W = (float)iw[0];
    const float H = (float)ih[0];
    const float4 p = *(const float4*)(prop + n * 4);
    const float pw = p.z - p.x, ph = p.w - p.y;
    const float pcx = p.x + 0.5f * pw, pcy = p.y + 0.5f * ph;

    for (int c = 1 + lane; c <= FG; c += 64) {
        float score = expf(lrow[c] - m) / e;   // match jax.nn.softmax (divide)
        const float4 d = *(const float4*)(reg + (long)n * (NC * 4) + c * 4);
        float dx = d.x / 10.0f;
        float dy = d.y / 10.0f;
        float dw = fminf(d.z / 5.0f, BBOX_CLIP);
        float dh = fminf(d.w / 5.0f, BBOX_CLIP);
        float ncx = dx * pw + pcx;
        float ncy = dy * ph + pcy;
        float nw = expf(dw) * pw;
        float nh = expf(dh) * ph;
        float bx1 = ncx - 0.5f * nw, by1 = ncy - 0.5f * nh;
        float bx2 = ncx + 0.5f * nw, by2 = ncy + 0.5f * nh;
        bx1 = fminf(fmaxf(bx1, 0.0f), W);
        by1 = fminf(fmaxf(by1, 0.0f), H);
        bx2 = fminf(fmaxf(bx2, 0.0f), W);
        by2 = fminf(fmaxf(by2, 0.0f), H);
        bool keep = ((bx2 - bx1) >= 1.0f) && ((by2 - by1) >= 1.0f);

        if (n == 0) {
            float* b0 = boxes0 + (c - 1) * 4;
            b0[0] = bx1; b0[1] = by1; b0[2] = bx2; b0[3] = by2;
        }
        if (score >= 0.05f && keep) {
            const int slot = (c - 1) * SH + shard;
            int pos = atomicAdd(&counts[slot * CPADI], 1);
            if (pos < CAPS) {
                float* cb = cbox + ((long)slot * CAPS + pos) * 4;
                cb[0] = bx1; cb[1] = by1; cb[2] = bx2; cb[3] = by2;
                cscore[slot * CAPS + pos] = score;
            }
        }
    }
}

// ---------------------------------------------------------------------------
// Kernel 2: sorted NMS via FULL symmetric suppression bit-matrix + parallel
// greedy fixpoint (replaces the serial wave-0 sweep of R1: ~100 dependent LDS
// round trips + ~700 serial scalar stores was the 40 us latency chain).
//
// Key identity: the triangular column view M[j][i] (j<i) of the greedy
// recursion equals the SYMMETRIC row i masked to bits j<i — so building full
// symmetric rows gives every lane its own column for free (no transpose).
// Fixpoint v[i] = !exists j<i: v[j] & M[i][j] converges to the unique greedy
// solution in <= chain-depth iterations (typically 3-5); early-exit on
// no-change is exact (F(v)=v implies v is THE solution).
// Output: lane-parallel bit-rank-select + float4 stores.
// ---------------------------------------------------------------------------
__global__ __launch_bounds__(1024) void nms_kernel(
    const int* __restrict__ counts,
    const float* __restrict__ boxes0,
    const float* __restrict__ cbox,
    const float* __restrict__ cscore,
    float* __restrict__ out)
{
    __shared__ __align__(16) float  s_sc[MAXK];     // unsorted scores
    __shared__ float4 s_ubox[MAXK];                 // unsorted boxes
    __shared__ int    s_sidx[MAXK];                 // rank -> unsorted idx
    __shared__ float4 s_box[MAXK];                  // sorted boxes
    __shared__ float  s_ss[MAXK];                   // sorted scores
    __shared__ unsigned long long s_row[MAXK * KROW];  // symmetric iou>thr rows

    const int c = blockIdx.x;       // class label = c+1
    const int t = threadIdx.x;
    const int lane = t & 63;
    const int wv = t >> 6;

    int cnt0 = min(counts[(c * SH + 0) * CPADI], CAPS);
    int cnt1 = min(counts[(c * SH + 1) * CPADI], CAPS);
    int cnt2 = min(counts[(c * SH + 2) * CPADI], CAPS);
    int cnt3 = min(counts[(c * SH + 3) * CPADI], CAPS);
    int cnt4 = min(counts[(c * SH + 4) * CPADI], CAPS);
    int cnt5 = min(counts[(c * SH + 5) * CPADI], CAPS);
    int cnt6 = min(counts[(c * SH + 6) * CPADI], CAPS);
    int cnt7 = min(counts[(c * SH + 7) * CPADI], CAPS);
    int K = cnt0 + cnt1 + cnt2 + cnt3 + cnt4 + cnt5 + cnt6 + cnt7;
    if (K > MAXK) K = MAXK;
    const int KW = (K + 63) >> 6;

    // NOTE: no s_row zeroing needed anymore — rows r<K get all words w<KW
    // written; everything else is masked by validity/below masks in the
    // fixpoint (garbage reads are harmless integers).

    // zero tails: scores (rank-sort float4 chunks read past K) and sorted
    // boxes (register columns j>=K become zero boxes -> iou==0 -> no bit)
    for (int i = K + t; i < MAXK; i += 1024) {
        s_sc[i] = 0.0f;
        s_ss[i] = 0.0f;
        s_box[i] = make_float4(0.f, 0.f, 0.f, 0.f);
    }
    // load: thread t handles shard s = t>>7, entry i = t&127
    {
        const int s = t >> 7;
        const int i = t & (CAPS - 1);
        int mycnt = cnt0;
        if (s == 1) mycnt = cnt1; if (s == 2) mycnt = cnt2;
        if (s == 3) mycnt = cnt3; if (s == 4) mycnt = cnt4;
        if (s == 5) mycnt = cnt5; if (s == 6) mycnt = cnt6;
        if (s == 7) mycnt = cnt7;
        int offs = 0;
        if (s > 0) offs += cnt0; if (s > 1) offs += cnt1;
        if (s > 2) offs += cnt2; if (s > 3) offs += cnt3;
        if (s > 4) offs += cnt4; if (s > 5) offs += cnt5;
        if (s > 6) offs += cnt6;
        if (i < mycnt) {
            int d = offs + i;
            if (d < MAXK) {
                const long src = (long)(c * SH + s) * CAPS + i;
                s_sc[d] = cscore[src];
                s_ubox[d] = *(const float4*)(cbox + src * 4);
            }
        }
    }
    __syncthreads();

    // counting-rank sort, float4-chunked score reads
    if (t < K) {
        const float si = s_sc[t];
        const float4* s4 = (const float4*)s_sc;
        const int nch = (K + 3) >> 2;
        int r = 0;
        for (int ch = 0; ch < nch; ++ch) {
            const float4 sj = s4[ch];
            const int j = ch * 4;
            r += (sj.x > si) || (sj.x == si && (j + 0) < t);
            r += (sj.y > si) || (sj.y == si && (j + 1) < t);
            r += (sj.z > si) || (sj.z == si && (j + 2) < t);
            r += (sj.w > si) || (sj.w == si && (j + 3) < t);
        }
        s_sidx[r] = t;
    }
    __syncthreads();

    if (t < K) {
        const int i = s_sidx[t];
        s_box[t] = s_ubox[i];
        s_ss[t] = s_sc[i];
    }
    __syncthreads();

    // register-resident columns: lane owns cols lane, 64+lane, ..., 320+lane
    float4 colb[KW6];
    float a2c[KW6];
#pragma unroll
    for (int w = 0; w < KW6; ++w) {
        const float4 b = s_box[w * 64 + lane];
        colb[w] = b;
        a2c[w] = (b.z - b.x) * (b.w - b.y);
    }

    // FULL symmetric suppression rows: row r, bit j set iff iou(r,j)>0.5.
    // (self-bit and j>i bits are masked off by the fixpoint's below-mask.)
    // iou expression kept bit-identical to reference (division, op order).
    for (int r = wv; r < K; r += 16) {
        const float4 rb = s_box[r];           // uniform b128 broadcast
        const float a1 = (rb.z - rb.x) * (rb.w - rb.y);
#pragma unroll
        for (int w = 0; w < KW6; ++w) {
            if (w < KW) {
                const float lx = fmaxf(rb.x, colb[w].x);
                const float ly = fmaxf(rb.y, colb[w].y);
                const float rx = fminf(rb.z, colb[w].z);
                const float ry = fminf(rb.w, colb[w].w);
                const float cw = fmaxf(rx - lx, 0.0f);
                const float ch = fmaxf(ry - ly, 0.0f);
                const float inter = cw * ch;
                const float iou = inter / (a1 + a2c[w] - inter + 1e-12f);
                const unsigned long long msk = __ballot(iou > 0.5f);
                if (lane == 0) s_row[r * KROW + w] = msk;
            }
        }
    }
    __syncthreads();

    if (wv != 0) return;    // fixpoint + output: wave 0 only

    // valid masks = bits i<K per word
#define INIW(W) ((K >= (W)*64 + 64) ? ~0ull : ((K <= (W)*64) ? 0ull : ((~0ull) >> (64 - (K - (W)*64)))))
    const unsigned long long va0 = INIW(0), va1 = INIW(1), va2 = INIW(2);
    const unsigned long long va3 = INIW(3), va4 = INIW(4), va5 = INIW(5);
#undef INIW

    const unsigned long long ltm = (1ull << lane) - 1ull;  // bits j<lane

    unsigned long long v0 = va0, v1 = va1, v2 = va2;
    unsigned long long v3 = va3, v4 = va4, v5 = va5;

    for (int it = 0; it < MAXK; ++it) {
        unsigned long long nv0, nv1, nv2, nv3, nv4, nv5;
        {   // wi = 0: column i = lane
            const unsigned long long* rp = s_row + (unsigned)(0 * 64 + lane) * KROW;
            unsigned long long s = rp[0] & v0 & ltm;
            nv0 = __ballot(s == 0ull) & va0;
        }
        {   // wi = 1: column i = 64 + lane
            const unsigned long long* rp = s_row + (unsigned)(1 * 64 + lane) * KROW;
            unsigned long long s = (rp[0] & v0) | (rp[1] & v1 & ltm);
            nv1 = __ballot(s == 0ull) & va1;
        }
        {   // wi = 2
            const unsigned long long* rp = s_row + (unsigned)(2 * 64 + lane) * KROW;
            unsigned long long s = (rp[0] & v0) | (rp[1] & v1) | (rp[2] & v2 & ltm);
            nv2 = __ballot(s == 0ull) & va2;
        }
        {   // wi = 3
            const unsigned long long* rp = s_row + (unsigned)(3 * 64 + lane) * KROW;
            unsigned long long s = (rp[0] & v0) | (rp[1] & v1) | (rp[2] & v2) |
                                   (rp[3] & v3 & ltm);
            nv3 = __ballot(s == 0ull) & va3;
        }
        {   // wi = 4
            const unsigned long long* rp = s_row + (unsigned)(4 * 64 + lane) * KROW;
            unsigned long long s = (rp[0] & v0) | (rp[1] & v1) | (rp[2] & v2) |
                                   (rp[3] & v3) | (rp[4] & v4 & ltm);
            nv4 = __ballot(s == 0ull) & va4;
        }
        {   // wi = 5
            const unsigned long long* rp = s_row + (unsigned)(5 * 64 + lane) * KROW;
            unsigned long long s = (rp[0] & v0) | (rp[1] & v1) | (rp[2] & v2) |
                                   (rp[3] & v3) | (rp[4] & v4) | (rp[5] & v5 & ltm);
            nv5 = __ballot(s == 0ull) & va5;
        }
        const unsigned long long diff = (nv0 ^ v0) | (nv1 ^ v1) | (nv2 ^ v2) |
                                        (nv3 ^ v3) | (nv4 ^ v4) | (nv5 ^ v5);
        v0 = nv0; v1 = nv1; v2 = nv2; v3 = nv3; v4 = nv4; v5 = nv5;
        if (diff == 0ull) break;   // F(v)=v -> unique greedy solution reached
    }

    // lane-parallel output: bit-rank-select the d-th kept box
    float* ob = out + (long)c * ND * 4;
    float* os = out + (long)FG * ND * 4 + c * ND;
    float* ol = os + FG * ND;
    float* ov = ol + FG * ND;
    const float lab = (float)(c + 1);

    const int p0 = __popcll(v0), p1 = __popcll(v1), p2 = __popcll(v2);
    const int p3 = __popcll(v3), p4 = __popcll(v4);
    const int total = p0 + p1 + p2 + p3 + p4 + __popcll(v5);
    const int kept = total < ND ? total : ND;

    const float b0x1 = boxes0[c * 4 + 0], b0y1 = boxes0[c * 4 + 1];
    const float b0x2 = boxes0[c * 4 + 2], b0y2 = boxes0[c * 4 + 3];

    for (int d = lane; d < ND; d += 64) {
        if (d < kept) {
            int rr = d;
            unsigned long long x;
            int wbase;
            if (rr < p0) { x = v0; wbase = 0; }
            else { rr -= p0;
                if (rr < p1) { x = v1; wbase = 64; }
                else { rr -= p1;
                    if (rr < p2) { x = v2; wbase = 128; }
                    else { rr -= p2;
                        if (rr < p3) { x = v3; wbase = 192; }
                        else { rr -= p3;
                            if (rr < p4) { x = v4; wbase = 256; }
                            else { rr -= p4; x = v5; wbase = 320; }
                        }
                    }
                }
            }
            for (int k = 0; k < rr; ++k) x &= x - 1ull;   // drop rr lowest set bits
            const int i_d = wbase + __builtin_ctzll(x);
            const float4 kb = s_box[i_d];
            *(float4*)(ob + d * 4) = kb;
            os[d] = s_ss[i_d]; ol[d] = lab; ov[d] = 1.0f;
        } else {
            *(float4*)(ob + d * 4) = make_float4(b0x1, b0y1, b0x2, b0y2);
            os[d] = 0.0f; ol[d] = lab; ov[d] = 0.0f;
        }
    }
}

extern "C" void kernel_launch(void* const* d_in, const int* in_sizes, int n_in,
                              void* d_out, int out_size, void* d_ws, size_t ws_size,
                              hipStream_t stream) {
    const float* prop  = (const float*)d_in[0];
    const float* logit = (const float*)d_in[1];
    const float* reg   = (const float*)d_in[2];
    const int*   ih    = (const int*)d_in[3];
    const int*   iw    = (const int*)d_in[4];
    float* out = (float*)d_out;

    char* ws = (char*)d_ws;
    int*   counts = (int*)ws;                        // FG*SH*CPADI ints (80 KB)
    float* boxes0 = (float*)(ws + 81920);            // FG*4 floats
    float* cscore = (float*)(ws + 90112);            // FG*SH*CAPS floats (320 KB)
    float* cbox   = (float*)(ws + 90112 + (size_t)FG * SH * CAPS * 4); // x4 (1.3 MB)

    hipMemsetAsync(counts, 0, FG * SH * CPADI * sizeof(int), stream);
    decode_kernel<<<NN / 4, 256, 0, stream>>>(prop, logit, reg, ih, iw,
                                              counts, boxes0, cbox, cscore);
    nms_kernel<<<FG, 1024, 0, stream>>>(counts, boxes0, cbox, cscore, out);
}